// Round 5
// baseline (118.545 us; speedup 1.0000x reference)
//
#include <hip/hip_runtime.h>

#define DEVINL __device__ __forceinline__

typedef _Float16 h2_t __attribute__((ext_vector_type(2)));

// ---------------------------------------------------------------------------
// 3-stage re-layout pipeline (all index algebra over GF(2), compile-time):
// Logical index bit position p <-> wire 9-p. CNOT ring = linear map C (row
// masks built exactly as in the R1/R2-verified convention: slot data fixed,
// Psi_post[C a] = Psi_pre[a]).
// Layout k (k=1,2,3): storage bit j <-> logical bit position POSk[j].
// Stage k applies 4 (or 2) Rot gates on storage reg bits 0..3 (pure register
// pairing, NO lane exchanges). Between stages: LDS scatter (packed f16) whose
// XOR-linear addressing performs the re-layout; gathers are contiguous b128.
// ---------------------------------------------------------------------------
constexpr unsigned P1[10] = {9,8,7,6,5,4,3,2,1,0};  // reg bits: wires 0,1,2,3
constexpr unsigned P2[10] = {3,2,1,0,5,4,9,8,7,6};  // reg bits: wires 6,7,8,9
constexpr unsigned P3[10] = {5,4,9,8,7,6,3,2,1,0};  // reg bits 0,1: wires 4,5

struct Maps2 {
  unsigned emb_j[6], emb_r[16];   // a -> loc1(C1*a)
  unsigned s12_j[6], s12_r[16];   // s1 -> loc2(B1*s1)
  unsigned s23_j[6], s23_r[16];   // s2 -> loc3(B2*s2)
  unsigned rho_l[10], rho_r[10];  // sign masks over s3 (lane part, reg part)
  bool ok;
};

constexpr unsigned mulF2(const unsigned* R, unsigned v) {
  unsigned o = 0;
  for (int i = 0; i < 10; ++i) o |= unsigned(__builtin_popcount(R[i] & v) & 1) << i;
  return o;
}
constexpr unsigned locP(const unsigned* P, unsigned L) {
  unsigned s = 0;
  for (int j = 0; j < 10; ++j) s |= ((L >> P[j]) & 1u) << j;
  return s;
}

constexpr Maps2 build2() {
  Maps2 M{};
  unsigned C1[10], C2[10];
  for (int i = 0; i < 10; ++i) { C1[i] = 1u << i; C2[i] = 1u << i; }
  for (int q = 0; q < 10; ++q) C1[9 - ((q + 1) % 10)] ^= C1[9 - q];
  for (int q = 0; q < 10; ++q) C2[9 - ((q + 2) % 10)] ^= C2[9 - q];

  unsigned embc[10], c12[10], c23[10];
  for (int j = 0; j < 10; ++j) embc[j] = locP(P1, mulF2(C1, 1u << j));
  for (int j = 0; j < 10; ++j) c12[j]  = locP(P2, 1u << P1[j]);
  for (int j = 0; j < 10; ++j) c23[j]  = locP(P3, 1u << P2[j]);

  for (int jj = 0; jj < 6; ++jj) {
    M.emb_j[jj] = embc[4 + jj];
    M.s12_j[jj] = c12[4 + jj];
    M.s23_j[jj] = c23[4 + jj];
  }
  for (int r = 0; r < 16; ++r) {
    unsigned a = 0, b = 0, c = 0;
    for (int k = 0; k < 4; ++k)
      if ((r >> k) & 1) { a ^= embc[k]; b ^= c12[k]; c ^= c23[k]; }
    M.emb_r[r] = a; M.s12_r[r] = b; M.s23_r[r] = c;
  }
  for (int q = 0; q < 10; ++q) {
    unsigned row = C2[9 - q], rho = 0;
    for (int j = 0; j < 10; ++j) rho |= ((row >> P3[j]) & 1u) << j;
    M.rho_r[q] = rho & 15u;
    M.rho_l[q] = rho >> 4;
  }

  // ---- consistency checks (all maps linear -> single-bit probes suffice)
  bool ok = true;
  // wire placement of reg bits per stage
  ok = ok && (9 - P1[0] == 0) && (9 - P1[1] == 1) && (9 - P1[2] == 2) && (9 - P1[3] == 3);
  ok = ok && (9 - P2[0] == 6) && (9 - P2[1] == 7) && (9 - P2[2] == 8) && (9 - P2[3] == 9);
  ok = ok && (9 - P3[0] == 4) && (9 - P3[1] == 5);
  // psi maps: applying columns to loc_k(L) must equal loc_{k+1}(L)
  for (int p = 0; p < 10; ++p) {
    unsigned L = 1u << p;
    unsigned s1 = locP(P1, L), s2 = 0;
    for (int j = 0; j < 10; ++j) if ((s1 >> j) & 1u) s2 ^= c12[j];
    ok = ok && (s2 == locP(P2, L));
    unsigned t2 = locP(P2, L), t3 = 0;
    for (int j = 0; j < 10; ++j) if ((t2 >> j) & 1u) t3 ^= c23[j];
    ok = ok && (t3 == locP(P3, L));
  }
  // rho: parity(rho & s3) == bit_{9-q}(C2 * B3 * s3), single-bit s3
  for (int q = 0; q < 10; ++q) {
    unsigned rho = M.rho_r[q] | (M.rho_l[q] << 4);
    for (int j = 0; j < 10; ++j) {
      unsigned b = 1u << P3[j];
      unsigned cc = mulF2(C2, b);
      ok = ok && (((cc >> (9 - q)) & 1u) == ((rho >> j) & 1u));
    }
  }
  M.ok = ok;
  return M;
}

constexpr Maps2 MM = build2();
static_assert(MM.ok, "index-map self-check failed");

DEVINL float csign(float v, int s) {
  return __int_as_float(__float_as_int(v) ^ (s << 31));
}
DEVINL int pk(float a, float b) {  // f16 pack: lo=a, hi=b
  return __builtin_bit_cast(int, __builtin_amdgcn_cvt_pkrtz(a, b));
}
template<int XOR>
DEVINL float lxf(float v, int lane) {
  int x = __float_as_int(v); int r;
  if constexpr (XOR == 1)      r = __builtin_amdgcn_update_dpp(0, x, 0xB1, 0xF, 0xF, true);
  else if constexpr (XOR == 2) r = __builtin_amdgcn_update_dpp(0, x, 0x4E, 0xF, 0xF, true);
  else if constexpr (XOR == 3) r = __builtin_amdgcn_update_dpp(0, x, 0x1B, 0xF, 0xF, true);
  else if constexpr (XOR < 32) r = __builtin_amdgcn_ds_swizzle(x, 0x1F | (XOR << 10));
  else                         r = __builtin_amdgcn_ds_bpermute((lane ^ XOR) << 2, x);
  return __int_as_float(r);
}

// Rot gate (u00=(m0,m1), u01=(m2,m3), u10=(-m2,m3), u11=(m0,-m1)) on reg bit BIT.
template<int BIT>
DEVINL void gate_bit(float (&ar)[16], float (&ai)[16], float m0, float m1, float m2, float m3) {
  #pragma unroll
  for (int r = 0; r < 16; ++r) {
    if (!(r & (1 << BIT))) {
      const int p = r | (1 << BIT);
      float xr = ar[r], xi = ai[r], yr = ar[p], yi = ai[p];
      ar[r] =  m0*xr - m1*xi + m2*yr - m3*yi;
      ai[r] =  m1*xr + m0*xi + m3*yr + m2*yi;
      ar[p] =  m0*yr + m1*yi - m2*xr - m3*xi;
      ai[p] = -m1*yr + m0*yi + m3*xr - m2*xi;
    }
  }
}

DEVINL void scatter16(const float (&ar)[16], const float (&ai)[16], int* buf,
                      int lc, const unsigned (&cols)[16]) {
  #pragma unroll
  for (int r = 0; r < 16; ++r) buf[lc ^ (int)cols[r]] = pk(ar[r], ai[r]);
}
DEVINL void gather16(float (&ar)[16], float (&ai)[16], const int* buf, int lane) {
  #pragma unroll
  for (int v = 0; v < 4; ++v) {
    int4 w4 = *(const int4*)(buf + lane * 16 + v * 4);
    int vv[4] = {w4.x, w4.y, w4.z, w4.w};
    #pragma unroll
    for (int d = 0; d < 4; ++d) {
      h2_t h = __builtin_bit_cast(h2_t, vv[d]);
      ar[v*4+d] = (float)h.x;
      ai[v*4+d] = (float)h.y;
    }
  }
}

__global__ __launch_bounds__(256) void qsim(const float* __restrict__ x,
                                            const float* __restrict__ qw,
                                            float* __restrict__ out, int B) {
  __shared__ __align__(16) float sm32[80];
  __shared__ __align__(16) int bufA[4][1024];
  __shared__ __align__(16) int bufB[4][1024];
  int tid = threadIdx.x;
  if (tid < 20) {
    float phi = qw[tid*3+0], th = qw[tid*3+1], om = qw[tid*3+2];
    float c = cosf(0.5f*th), s = sinf(0.5f*th);
    float apo = 0.5f*(phi+om), amo = 0.5f*(phi-om);
    sm32[tid*4+0] =  cosf(apo)*c;   // u00 re
    sm32[tid*4+1] = -sinf(apo)*c;   // u00 im
    sm32[tid*4+2] = -cosf(amo)*s;   // u01 re
    sm32[tid*4+3] = -sinf(amo)*s;   // u01 im
  }
  __syncthreads();

  int lane = tid & 63, wv = tid >> 6;
  int bidx = __builtin_amdgcn_readfirstlane(blockIdx.x*4 + wv);
  int bld = bidx < B ? bidx : (B - 1);

  // ---- embedding + layer-0 Rot folded into per-wire complex factors (fp32)
  // (verified in R2). Produces Psi1[a], a = r | (lane<<4), wire w <-> a bit 9-w.
  const float* xb = x + bld * 10;
  float f0r[10], f0i[10], f1r[10], f1i[10];
  #pragma unroll
  for (int w = 0; w < 10; ++w) {
    float h = 0.5f * xb[w];
    float s = __sinf(h), c = __cosf(h);
    float m0 = sm32[w*4+0], m1 = sm32[w*4+1], m2 = sm32[w*4+2], m3 = sm32[w*4+3];
    f0r[w] =  m0*c + m2*s;
    f0i[w] =  m1*c + m3*s;
    f1r[w] = -m2*c + m0*s;
    f1i[w] =  m3*c - m1*s;
  }
  float lfr, lfi;
  {
    int bit = lane & 1;
    lfr = bit ? f1r[5] : f0r[5];
    lfi = bit ? f1i[5] : f0i[5];
  }
  #pragma unroll
  for (int jj = 1; jj < 6; ++jj) {
    int w = 5 - jj;
    int bit = (lane >> jj) & 1;
    float pr = bit ? f1r[w] : f0r[w];
    float pi = bit ? f1i[w] : f0i[w];
    float nr = lfr*pr - lfi*pi;
    float ni = lfr*pi + lfi*pr;
    lfr = nr; lfi = ni;
  }
  float t01r[4], t01i[4], t23r[4], t23i[4];
  #pragma unroll
  for (int v = 0; v < 4; ++v) {
    float ar9 = (v&1)? f1r[9]:f0r[9], ai9 = (v&1)? f1i[9]:f0i[9];
    float ar8 = (v>>1)? f1r[8]:f0r[8], ai8 = (v>>1)? f1i[8]:f0i[8];
    t01r[v] = ar9*ar8 - ai9*ai8;
    t01i[v] = ar9*ai8 + ai9*ar8;
    float ar7 = (v&1)? f1r[7]:f0r[7], ai7 = (v&1)? f1i[7]:f0i[7];
    float ar6 = (v>>1)? f1r[6]:f0r[6], ai6 = (v>>1)? f1i[6]:f0i[6];
    t23r[v] = ar7*ar6 - ai7*ai6;
    t23i[v] = ar7*ai6 + ai7*ar6;
  }
  float g4r[4], g4i[4];
  #pragma unroll
  for (int v = 0; v < 4; ++v) {
    g4r[v] = lfr*t01r[v] - lfi*t01i[v];
    g4i[v] = lfr*t01i[v] + lfi*t01r[v];
  }

  // per-lane XOR-affine address parts
  int lcE = 0, lc12 = 0, lc23 = 0;
  #pragma unroll
  for (int jj = 0; jj < 6; ++jj) {
    int bit = (lane >> jj) & 1;
    lcE  ^= bit ? (int)MM.emb_j[jj] : 0;
    lc12 ^= bit ? (int)MM.s12_j[jj] : 0;
    lc23 ^= bit ? (int)MM.s23_j[jj] : 0;
  }

  // embed-out scatter into layout 1 (folds the layer-0 CNOT ring C1)
  #pragma unroll
  for (int r = 0; r < 16; ++r) {
    float er = g4r[r&3]*t23r[r>>2] - g4i[r&3]*t23i[r>>2];
    float ei = g4r[r&3]*t23i[r>>2] + g4i[r&3]*t23r[r>>2];
    bufA[wv][lcE ^ (int)MM.emb_r[r]] = pk(er, ei);
  }
  __syncthreads();

  float ar[16], ai[16];
  gather16(ar, ai, &bufA[wv][0], lane);

  // ---- stage 1: wires 0..3 (reg bits 0..3 of layout 1)
  {
    float4 c0 = *(const float4*)(sm32 + 10*4);
    float4 c1 = *(const float4*)(sm32 + 11*4);
    float4 c2 = *(const float4*)(sm32 + 12*4);
    float4 c3 = *(const float4*)(sm32 + 13*4);
    gate_bit<0>(ar, ai, c0.x, c0.y, c0.z, c0.w);
    gate_bit<1>(ar, ai, c1.x, c1.y, c1.z, c1.w);
    gate_bit<2>(ar, ai, c2.x, c2.y, c2.z, c2.w);
    gate_bit<3>(ar, ai, c3.x, c3.y, c3.z, c3.w);
  }
  scatter16(ar, ai, &bufB[wv][0], lc12, MM.s12_r);
  __syncthreads();
  gather16(ar, ai, &bufB[wv][0], lane);

  // ---- stage 2: wires 6..9 (reg bits 0..3 of layout 2)
  {
    float4 c0 = *(const float4*)(sm32 + 16*4);
    float4 c1 = *(const float4*)(sm32 + 17*4);
    float4 c2 = *(const float4*)(sm32 + 18*4);
    float4 c3 = *(const float4*)(sm32 + 19*4);
    gate_bit<0>(ar, ai, c0.x, c0.y, c0.z, c0.w);
    gate_bit<1>(ar, ai, c1.x, c1.y, c1.z, c1.w);
    gate_bit<2>(ar, ai, c2.x, c2.y, c2.z, c2.w);
    gate_bit<3>(ar, ai, c3.x, c3.y, c3.z, c3.w);
  }
  scatter16(ar, ai, &bufA[wv][0], lc23, MM.s23_r);
  __syncthreads();
  gather16(ar, ai, &bufA[wv][0], lane);

  // ---- stage 3: wires 4,5 (reg bits 0,1 of layout 3)
  {
    float4 c0 = *(const float4*)(sm32 + 14*4);
    float4 c1 = *(const float4*)(sm32 + 15*4);
    gate_bit<0>(ar, ai, c0.x, c0.y, c0.z, c0.w);
    gate_bit<1>(ar, ai, c1.x, c1.y, c1.z, c1.w);
  }

  // ---- tail: probs, WHT over the 4 reg bits, sign masks (fold C2), reduce
  float t[16];
  #pragma unroll
  for (int r = 0; r < 16; ++r) t[r] = ar[r]*ar[r] + ai[r]*ai[r];
  #pragma unroll
  for (int bit = 1; bit < 16; bit <<= 1) {
    #pragma unroll
    for (int i = 0; i < 16; ++i) {
      if ((i & bit) == 0) {
        float u = t[i], v = t[i|bit];
        t[i] = u + v;
        t[i|bit] = u - v;
      }
    }
  }
  float e[10];
  #pragma unroll
  for (int q = 0; q < 10; ++q) {
    int sl = __popc(unsigned(lane & (int)MM.rho_l[q])) & 1;
    e[q] = csign(t[MM.rho_r[q]], sl);
  }
  #pragma unroll
  for (int q = 0; q < 10; ++q) {
    e[q] += lxf<1>(e[q], lane);
    e[q] += lxf<2>(e[q], lane);
    e[q] += lxf<4>(e[q], lane);
    e[q] += lxf<8>(e[q], lane);
    e[q] += lxf<16>(e[q], lane);
    e[q] += lxf<32>(e[q], lane);
  }
  float v = e[0];
  #pragma unroll
  for (int q = 1; q < 10; ++q) v = (lane == q) ? e[q] : v;
  if (bidx < B && lane < 10) out[bidx * 10 + lane] = v;
}

extern "C" void kernel_launch(void* const* d_in, const int* in_sizes, int n_in,
                              void* d_out, int out_size, void* d_ws, size_t ws_size,
                              hipStream_t stream) {
  const float* x  = (const float*)d_in[0];
  const float* qw = (const float*)d_in[1];
  float* out = (float*)d_out;
  int B = in_sizes[0] / 10;
  int blocks = (B + 3) / 4;   // 4 samples (waves) per 256-thread block
  hipLaunchKernelGGL(qsim, dim3(blocks), dim3(256), 0, stream, x, qw, out, B);
}